// Round 1
// 266.837 us; speedup vs baseline: 1.1407x; 1.1407x over previous
//
#include <hip/hip_runtime.h>
#include <stdint.h>

// out[M,N] = x[M,K] @ dequant(W_q_packed)[K,N] + bias[N]
// M=N=K=4096, 4-bit nibbles packed 8/int32 along K, GROUP=128.
// R6: GEMM rewritten as 256x256-tile, BK=64, 8-wave (2x4), 4-phase-per-K-tile
// schedule (T3+T4+T5): per phase {ds_read frags || issue global_load_lds
// prefetch || barrier || setprio(1) 16xMFMA setprio(0) || barrier}; tile t+1
// staged during phases 1-2 of tile t, single vmcnt(0) drain per tile at
// phase-4 end (~3 phases after issue -> latency hidden). LDS 128KB dbuf,
// zero-conflict XOR-cell layout (pre-swizzled global src, swizzled ds_read).
// XCD swizzle: each XCD owns 2 B-panels (4MB = its L2), sweeps 16 M-tiles.

#define M_DIM 4096
#define N_DIM 4096
#define K_DIM 4096

typedef __attribute__((ext_vector_type(8))) short short8;
typedef __attribute__((ext_vector_type(4))) float f32x4;

__device__ __forceinline__ unsigned short f2bf(float f) {
  uint32_t u = __builtin_bit_cast(uint32_t, f);
  u += 0x7fffu + ((u >> 16) & 1u);   // round-to-nearest-even
  return (unsigned short)(u >> 16);
}

// ---------- kernel 1: fused prep (unchanged) ----------
// blocks [0,2048): x fp32 -> bf16 (ushort8 stores).
// blocks [2048,3072): dequant + transpose -> W^T (N x K) bf16.
__global__ __launch_bounds__(256) void prep_kernel(const float* __restrict__ x,
                                                   unsigned short* __restrict__ xb,
                                                   const int* __restrict__ Wq,
                                                   const float* __restrict__ scales,
                                                   const float* __restrict__ zeros,
                                                   unsigned short* __restrict__ wt) {
  __shared__ uint4 Ts[32 * 64];  // 32 KB (dequant slice only)
  const int tid = threadIdx.x;
  if (blockIdx.x < 2048) {
    const int total = (M_DIM * K_DIM) / 8;   // 2M ushort8
    const float4* x4 = (const float4*)x;
    uint4* o8 = (uint4*)xb;
#pragma unroll
    for (int p = 0; p < 4; ++p) {
      int i = (p * 2048 + blockIdx.x) * 256 + tid;
      if (i < total) {
        float4 a = x4[2 * i], b = x4[2 * i + 1];
        uint4 o;
        o.x = (uint32_t)f2bf(a.x) | ((uint32_t)f2bf(a.y) << 16);
        o.y = (uint32_t)f2bf(a.z) | ((uint32_t)f2bf(a.w) << 16);
        o.z = (uint32_t)f2bf(b.x) | ((uint32_t)f2bf(b.y) << 16);
        o.w = (uint32_t)f2bf(b.z) | ((uint32_t)f2bf(b.w) << 16);
        o8[i] = o;
      }
    }
    return;
  }
  const int blk = blockIdx.x - 2048;
  const int n0 = (blk & 127) * 32;        // N/32 = 128 tiles
  const int gk0 = (blk >> 7) * 64;        // (K/8)/64 = 8 tiles

#pragma unroll
  for (int p = 0; p < 8; ++p) {
    int e = p * 256 + tid;
    int n_l = e & 31;
    int gk_l = e >> 5;
    int gk = gk0 + gk_l;
    int n = n0 + n_l;
    int g = gk >> 4;                // group = (gk*8)/128
    uint32_t q = (uint32_t)Wq[gk * N_DIM + n];
    float s = scales[g * N_DIM + n];
    float z = zeros[g * N_DIM + n];
    unsigned short b[8];
#pragma unroll
    for (int j = 0; j < 8; ++j) {
      float f = ((float)((q >> (4 * j)) & 15u) - z) * s;
      b[j] = f2bf(f);
    }
    uint4 cell;
    cell.x = (uint32_t)b[0] | ((uint32_t)b[1] << 16);
    cell.y = (uint32_t)b[2] | ((uint32_t)b[3] << 16);
    cell.z = (uint32_t)b[4] | ((uint32_t)b[5] << 16);
    cell.w = (uint32_t)b[6] | ((uint32_t)b[7] << 16);
    Ts[n_l * 64 + (gk_l ^ (n_l & 7))] = cell;
  }
  __syncthreads();
  uint4* dst = (uint4*)wt;
#pragma unroll
  for (int p = 0; p < 8; ++p) {
    int n_l = p * 4 + (tid >> 6);
    int gk_l = tid & 63;
    uint4 cell = Ts[n_l * 64 + (gk_l ^ (n_l & 7))];
    dst[(size_t)(n0 + n_l) * (K_DIM / 8) + (gk0 + gk_l)] = cell;
  }
}

// ---------- kernel 2: bf16 GEMM, C = A @ Bt^T + bias ----------
// 256x256 tile, 8 waves (wm 0..1, wn 0..3), each wave 128x64 output =
// acc[8][4] of 16x16x32 MFMA. BK=64, double-buffered 2x(32+32)KB LDS.
// LDS cell layout (16B cells): cell = row*8 + (kc ^ (row&7)); staging writes
// lane-linear dest with pre-swizzled global source (both-sides involution).

// stage one 256x64 bf16 tile (A or B) = 4 collective global_load_lds
#define STAGE4(DST, SRC)                                                         \
  {                                                                              \
    _Pragma("unroll") for (int j = 0; j < 4; ++j)                                \
        __builtin_amdgcn_global_load_lds(                                        \
            (const __attribute__((address_space(1))) void*)((SRC) +              \
                                                            (size_t)j * 64 * K_DIM), \
            (__attribute__((address_space(3))) void*)((DST) + tid + j * 512),    \
            16, 0, 0);                                                           \
  }

#define LOADA(QM)                                                                \
  {                                                                              \
    _Pragma("unroll") for (int mi = 0; mi < 4; ++mi) {                           \
      af[mi][0] = ASb[a_base + ((QM) * 4 + mi) * 128 + kx0];                     \
      af[mi][1] = ASb[a_base + ((QM) * 4 + mi) * 128 + kx1];                     \
    }                                                                            \
  }

#define LOADB(QN)                                                                \
  {                                                                              \
    _Pragma("unroll") for (int ni = 0; ni < 2; ++ni) {                           \
      bv[ni][0] = BSb[b_base + ((QN) * 2 + ni) * 128 + kx0];                     \
      bv[ni][1] = BSb[b_base + ((QN) * 2 + ni) * 128 + kx1];                     \
    }                                                                            \
  }

#define MFMA16(QM, QN)                                                           \
  {                                                                              \
    _Pragma("unroll") for (int mi = 0; mi < 4; ++mi)                             \
        _Pragma("unroll") for (int ni = 0; ni < 2; ++ni) {                       \
      acc[(QM) * 4 + mi][(QN) * 2 + ni] = __builtin_amdgcn_mfma_f32_16x16x32_bf16( \
          af[mi][0], bv[ni][0], acc[(QM) * 4 + mi][(QN) * 2 + ni], 0, 0, 0);     \
      acc[(QM) * 4 + mi][(QN) * 2 + ni] = __builtin_amdgcn_mfma_f32_16x16x32_bf16( \
          af[mi][1], bv[ni][1], acc[(QM) * 4 + mi][(QN) * 2 + ni], 0, 0, 0);     \
    }                                                                            \
  }

#define PHASE_MFMA(QM, QN)                                                       \
  {                                                                              \
    __builtin_amdgcn_s_barrier();                                                \
    __builtin_amdgcn_s_setprio(1);                                               \
    MFMA16(QM, QN);                                                              \
    __builtin_amdgcn_s_setprio(0);                                               \
    __builtin_amdgcn_s_barrier();                                                \
  }

__global__ __launch_bounds__(512, 2) void gemm_bt_kernel(
    const unsigned short* __restrict__ A, const unsigned short* __restrict__ Bt,
    const float* __restrict__ bias, float* __restrict__ C) {
  __shared__ short8 As[2 * 2048];  // 64 KB (2 buffers x 256 rows x 8 cells)
  __shared__ short8 Bs[2 * 2048];  // 64 KB

  const int tid = threadIdx.x;
  const int lane = tid & 63;
  const int w = tid >> 6;      // 0..7
  const int wm = w >> 2;       // 0..1
  const int wn = w & 3;        // 0..3

  // XCD swizzle: 256 blocks; xcd owns nt in {2*xcd, 2*xcd+1} (4MB of B = L2)
  const int b = blockIdx.x;
  const int xcd = b & 7;
  const int loc = b >> 3;              // 0..31
  const int nt = xcd * 2 + (loc & 1);  // 0..15
  const int mt = loc >> 1;             // 0..15
  const int m0 = mt * 256;
  const int n0 = nt * 256;

  // staging: thread covers cells tid + j*512 (j=0..3); decode cell -> (row,kc)
  const int srow = tid >> 3;                       // base row 0..63 (+64 per j)
  const int skc = (tid & 7) ^ (srow & 7);          // invariant across j (row step 64)
  const unsigned short* Ablk = A + (size_t)m0 * K_DIM + (size_t)srow * K_DIM + skc * 8;
  const unsigned short* Bblk = Bt + (size_t)n0 * K_DIM + (size_t)srow * K_DIM + skc * 8;

  // fragment read addressing
  const int fr = lane & 15;            // row-low (A) / col-low (B)
  const int fc = lane >> 4;            // k-quarter 0..3
  const int frx = fr & 7;
  const int a_base = (wm * 128 + fr) * 8;
  const int b_base = (wn * 64 + fr) * 8;
  const int kx0 = fc ^ frx;            // k-step 0
  const int kx1 = (4 + fc) ^ frx;      // k-step 1

  f32x4 acc[8][4] = {};
  short8 af[4][2];
  short8 bv[2][2];

  // prologue: stage tile 0 into buf0, drain, barrier
  STAGE4(As, Ablk);
  STAGE4(Bs, Bblk);
  asm volatile("s_waitcnt vmcnt(0)" ::: "memory");
  __builtin_amdgcn_s_barrier();

  for (int kt = 0; kt < K_DIM / 64; ++kt) {
    const int cur = kt & 1;
    const short8* ASb = As + cur * 2048;
    const short8* BSb = Bs + cur * 2048;
    short8* Anx = As + (cur ^ 1) * 2048;
    short8* Bnx = Bs + (cur ^ 1) * 2048;
    const bool pf = (kt + 1 < K_DIM / 64);
    const size_t knext = (size_t)(kt + 1) * 64;

    // phase 1: quad (m-lo, n-lo); issue A prefetch for tile kt+1
    LOADA(0);
    LOADB(0);
    if (pf) STAGE4(Anx, Ablk + knext);
    PHASE_MFMA(0, 0);

    // phase 2: quad (m-lo, n-hi); issue B prefetch for tile kt+1
    LOADB(1);
    if (pf) STAGE4(Bnx, Bblk + knext);
    PHASE_MFMA(0, 1);

    // phase 3: quad (m-hi, n-hi)
    LOADA(1);
    PHASE_MFMA(1, 1);

    // phase 4: quad (m-hi, n-lo); tile-end: drain prefetch (issued ~3 phases
    // ago -> latency hidden), then the barrier that publishes buf^1
    LOADB(0);
    __builtin_amdgcn_s_barrier();
    __builtin_amdgcn_s_setprio(1);
    MFMA16(1, 0);
    __builtin_amdgcn_s_setprio(0);
    asm volatile("s_waitcnt vmcnt(0)" ::: "memory");
    __builtin_amdgcn_s_barrier();
  }

  // epilogue: C/D layout col=lane&15, row=(lane>>4)*4+reg
  const int rr = (lane >> 4) * 4;
#pragma unroll
  for (int ni = 0; ni < 4; ++ni) {
    const int gn = n0 + wn * 64 + ni * 16 + fr;
    const float bvv = bias[gn];
#pragma unroll
    for (int mi = 0; mi < 8; ++mi) {
      const int gm = m0 + wm * 128 + mi * 16 + rr;
#pragma unroll
      for (int r = 0; r < 4; ++r)
        C[(size_t)(gm + r) * N_DIM + gn] = acc[mi][ni][r] + bvv;
    }
  }
}

extern "C" void kernel_launch(void* const* d_in, const int* in_sizes, int n_in,
                              void* d_out, int out_size, void* d_ws, size_t ws_size,
                              hipStream_t stream) {
  const float* x = (const float*)d_in[0];
  const int* wq = (const int*)d_in[1];
  const float* sc = (const float*)d_in[2];
  const float* zr = (const float*)d_in[3];
  const float* bias = (const float*)d_in[4];
  float* out = (float*)d_out;

  unsigned short* xb = (unsigned short*)d_ws;
  unsigned short* wt = (unsigned short*)((char*)d_ws + (size_t)M_DIM * K_DIM * 2);

  prep_kernel<<<dim3(3072), dim3(256), 0, stream>>>(x, xb, wq, sc, zr, wt);
  gemm_bt_kernel<<<dim3(256), dim3(512), 0, stream>>>(xb, wt, bias, out);
}